// Round 1
// baseline (1280.265 us; speedup 1.0000x reference)
//
#include <hip/hip_runtime.h>
#include <math.h>

#define NM 50000
#define ND 50000
#define NN 100000   // total nodes
#define DK 256      // feature dim of both sims
#define F  64       // attn feature size
#define SLOPE 0.2f

// ---------------- projection: z = [m_sim @ Wm^T ; d_sim @ Wd^T] ----------------
__global__ __launch_bounds__(256) void proj_kernel(const float* __restrict__ m_sim,
                                                   const float* __restrict__ d_sim,
                                                   const float* __restrict__ Wm,
                                                   const float* __restrict__ Wd,
                                                   float* __restrict__ z) {
    int tid  = threadIdx.x;
    int row  = blockIdx.x * 4 + (tid >> 6);
    int f    = tid & 63;
    const float* sim;
    const float* W;
    if (row < NM) { sim = m_sim + (size_t)row * DK;        W = Wm; }
    else          { sim = d_sim + (size_t)(row - NM) * DK; W = Wd; }
    const float4* s4 = (const float4*)sim;
    const float4* w4 = (const float4*)(W + f * DK);
    float acc = 0.f;
    #pragma unroll 8
    for (int k = 0; k < DK / 4; ++k) {
        float4 a = s4[k];
        float4 b = w4[k];
        acc += a.x * b.x + a.y * b.y + a.z * b.z + a.w * b.w;
    }
    z[(size_t)row * F + f] = acc;
}

// ---------------- degree histogram over dst ----------------
__global__ void hist_kernel(const int* __restrict__ dst, int* __restrict__ deg, int E) {
    int k = blockIdx.x * blockDim.x + threadIdx.x;
    if (k < E) atomicAdd(&deg[dst[k]], 1);
}

// ---------------- block-level inclusive scan (1024 elems / block) ----------------
__global__ __launch_bounds__(256) void scanA(const int* __restrict__ deg,
                                             int* __restrict__ incl,   // = offs+1
                                             int* __restrict__ bsums) {
    __shared__ int sd[256];
    int tid  = threadIdx.x;
    int base = blockIdx.x * 1024 + tid * 4;
    int v[4];
    int run = 0;
    #pragma unroll
    for (int j = 0; j < 4; ++j) {
        int i = base + j;
        int x = (i < NN) ? deg[i] : 0;
        run += x;
        v[j] = run;
    }
    sd[tid] = run;
    __syncthreads();
    for (int off = 1; off < 256; off <<= 1) {
        int t = (tid >= off) ? sd[tid - off] : 0;
        __syncthreads();
        sd[tid] += t;
        __syncthreads();
    }
    int texcl = sd[tid] - run;   // exclusive prefix of this thread within block
    #pragma unroll
    for (int j = 0; j < 4; ++j) {
        int i = base + j;
        if (i < NN) incl[i] = texcl + v[j];
    }
    if (tid == 255) bsums[blockIdx.x] = sd[255];
}

// ---------------- scan of the 98 block sums (exclusive, in place) ----------------
__global__ void scanB(int* __restrict__ bsums, int nb) {
    __shared__ int sd[128];
    int tid = threadIdx.x;
    int x = (tid < nb) ? bsums[tid] : 0;
    sd[tid] = x;
    __syncthreads();
    for (int off = 1; off < 128; off <<= 1) {
        int t = (tid >= off) ? sd[tid - off] : 0;
        __syncthreads();
        sd[tid] += t;
        __syncthreads();
    }
    if (tid < nb) bsums[tid] = sd[tid] - x;   // exclusive
}

// ---------------- finalize offsets + init scatter cursors ----------------
__global__ __launch_bounds__(256) void scanC(int* __restrict__ offs,
                                             int* __restrict__ cursor,
                                             const int* __restrict__ bsums,
                                             const int* __restrict__ deg) {
    int base = blockIdx.x * 1024 + threadIdx.x * 4;
    int add  = bsums[blockIdx.x];
    #pragma unroll
    for (int j = 0; j < 4; ++j) {
        int i = base + j;
        if (i < NN) {
            int v = offs[i + 1] + add;
            offs[i + 1] = v;
            cursor[i]   = v - deg[i];   // exclusive offset = start of segment i
        }
    }
    if (blockIdx.x == 0 && threadIdx.x == 0) offs[0] = 0;
}

// ---------------- scatter edges into CSR by dst ----------------
__global__ void scatter_kernel(const int* __restrict__ src, const int* __restrict__ dst,
                               int* __restrict__ cursor, int* __restrict__ csr_src, int E) {
    int k = blockIdx.x * blockDim.x + threadIdx.x;
    if (k < E) {
        int d   = dst[k];
        int pos = atomicAdd(&cursor[d], 1);
        csr_src[pos] = src[k];
    }
}

// ---------------- fused per-dst-node: scores + online softmax + aggregation + elu ----------------
__global__ __launch_bounds__(256) void gat_kernel(const float* __restrict__ z,
                                                  const int* __restrict__ offs,
                                                  const int* __restrict__ csr_src,
                                                  float* __restrict__ out) {
    int tid  = threadIdx.x;
    int node = blockIdx.x * 4 + (tid >> 6);   // one wave per node
    int lane = tid & 63;
    int beg = offs[node];
    int end = offs[node + 1];
    float zd = z[(size_t)node * F + lane];
    float m = -INFINITY, ssum = 0.f, h = 0.f;
    for (int j = beg; j < end; ++j) {
        int s    = csr_src[j];
        float zs = z[(size_t)s * F + lane];
        float p  = zs * zd;
        #pragma unroll
        for (int o = 32; o > 0; o >>= 1) p += __shfl_xor(p, o, 64);
        float e  = (p > 0.f) ? p : SLOPE * p;       // leaky_relu
        float nm = fmaxf(m, e);
        float sc = __expf(m - nm);                  // exp(-inf)=0 on first edge
        float ex = __expf(e - nm);
        ssum = ssum * sc + ex;
        h    = h * sc + ex * zs;
        m    = nm;
    }
    float o = (end > beg) ? (h / ssum) : 0.f;
    o = (o > 0.f) ? o : (__expf(o) - 1.f);          // elu (elu(0)=0)
    out[(size_t)node * F + lane] = o;
}

extern "C" void kernel_launch(void* const* d_in, const int* in_sizes, int n_in,
                              void* d_out, int out_size, void* d_ws, size_t ws_size,
                              hipStream_t stream) {
    const float* m_sim = (const float*)d_in[0];
    const float* d_sim = (const float*)d_in[1];
    const float* Wm    = (const float*)d_in[2];
    const float* Wd    = (const float*)d_in[3];
    const int*   src   = (const int*)d_in[4];
    const int*   dst   = (const int*)d_in[5];
    int E = in_sizes[4];
    float* out = (float*)d_out;

    char* ws = (char*)d_ws;
    float* z      = (float*)ws; ws += (size_t)NN * F * 4;
    int*   deg    = (int*)ws;   ws += (size_t)NN * 4;
    int*   offs   = (int*)ws;   ws += (size_t)(NN + 1) * 4;
    int*   cursor = (int*)ws;   ws += (size_t)NN * 4;
    int*   bsums  = (int*)ws;   ws += 128 * 4;
    int*   csr    = (int*)ws;   ws += (size_t)E * 4;

    hipMemsetAsync(deg, 0, (size_t)NN * 4, stream);

    proj_kernel<<<NN / 4, 256, 0, stream>>>(m_sim, d_sim, Wm, Wd, z);
    hist_kernel<<<(E + 255) / 256, 256, 0, stream>>>(dst, deg, E);
    int nb = (NN + 1023) / 1024;   // 98
    scanA<<<nb, 256, 0, stream>>>(deg, offs + 1, bsums);
    scanB<<<1, 128, 0, stream>>>(bsums, nb);
    scanC<<<nb, 256, 0, stream>>>(offs, cursor, bsums, deg);
    scatter_kernel<<<(E + 255) / 256, 256, 0, stream>>>(src, dst, cursor, csr, E);
    gat_kernel<<<NN / 4, 256, 0, stream>>>(z, offs, csr, out);
}

// Round 2
// 594.893 us; speedup vs baseline: 2.1521x; 2.1521x over previous
//
#include <hip/hip_runtime.h>
#include <math.h>

#define NM 50000
#define ND 50000
#define NN 100000   // total nodes
#define DK 256      // feature dim of both sims
#define F  64       // attn feature size
#define SLOPE 0.2f

#define BR  128     // rows per block tile
#define BK  64      // k-chunk
#define NBM 391     // ceil(NM / BR)
#define NBD 391     // ceil(ND / BR)

// ---------------- projection: z = [m_sim @ Wm^T ; d_sim @ Wd^T] ----------------
// Tiled fp32 GEMM: 128x64 tile, BK=64, LDS-staged A and W with XOR-16B swizzle,
// 8x4 register blocking per thread (256 threads = 16 tx * 16 ty).
__global__ __launch_bounds__(256) void proj_kernel(const float* __restrict__ m_sim,
                                                   const float* __restrict__ d_sim,
                                                   const float* __restrict__ Wm,
                                                   const float* __restrict__ Wd,
                                                   float* __restrict__ z) {
    __shared__ float As[BR * BK];   // 32 KB, row-major 64 words/row, quad-swizzled
    __shared__ float Ws[F * BK];    // 16 KB

    int bid  = blockIdx.x;
    bool ism = bid < NBM;
    const float* sim = ism ? m_sim : d_sim;
    const float* W   = ism ? Wm : Wd;
    int row0   = (ism ? bid : bid - NBM) * BR;
    int nrows  = ism ? NM : ND;
    int zbase  = ism ? 0 : NM;

    int t  = threadIdx.x;
    int tx = t & 15;     // col group
    int ty = t >> 4;     // row group
    int qt = t & 15;     // staging quad
    int rt = t >> 4;     // staging row-within-group

    float acc[8][4];
    #pragma unroll
    for (int i = 0; i < 8; ++i)
        #pragma unroll
        for (int j = 0; j < 4; ++j) acc[i][j] = 0.f;

    for (int k0 = 0; k0 < DK; k0 += BK) {
        // ---- stage A tile: 128 rows x 64 floats, swizzled quads ----
        #pragma unroll
        for (int it = 0; it < 8; ++it) {
            int r  = it * 16 + rt;                        // 0..127
            int gr = row0 + r; if (gr > nrows - 1) gr = nrows - 1;
            float4 v = ((const float4*)(sim + (size_t)gr * DK + k0))[qt];
            *(float4*)&As[r * BK + ((qt ^ (r & 7)) << 2)] = v;
        }
        // ---- stage W tile: 64 rows x 64 floats ----
        #pragma unroll
        for (int it = 0; it < 4; ++it) {
            int wr = it * 16 + rt;                        // 0..63
            float4 v = ((const float4*)(W + (size_t)wr * DK + k0))[qt];
            *(float4*)&Ws[wr * BK + ((qt ^ (wr & 7)) << 2)] = v;
        }
        __syncthreads();

        // ---- compute: 16 quad-steps, 8x4 register tile ----
        #pragma unroll
        for (int k4 = 0; k4 < 16; ++k4) {
            float4 a[8], w[4];
            #pragma unroll
            for (int i = 0; i < 8; ++i) {
                int r = i * 16 + ty;                      // r&7 == ty&7
                a[i] = *(const float4*)&As[r * BK + ((k4 ^ (ty & 7)) << 2)];
            }
            #pragma unroll
            for (int j = 0; j < 4; ++j) {
                int c = j * 16 + tx;                      // c&7 == tx&7
                w[j] = *(const float4*)&Ws[c * BK + ((k4 ^ (tx & 7)) << 2)];
            }
            #pragma unroll
            for (int i = 0; i < 8; ++i)
                #pragma unroll
                for (int j = 0; j < 4; ++j)
                    acc[i][j] += a[i].x * w[j].x + a[i].y * w[j].y
                               + a[i].z * w[j].z + a[i].w * w[j].w;
        }
        __syncthreads();
    }

    // ---- store ----
    #pragma unroll
    for (int i = 0; i < 8; ++i) {
        int r = row0 + i * 16 + ty;
        if (r < nrows) {
            float* zr = z + (size_t)(zbase + r) * F;
            #pragma unroll
            for (int j = 0; j < 4; ++j) zr[j * 16 + tx] = acc[i][j];
        }
    }
}

// ---------------- degree histogram over dst ----------------
__global__ void hist_kernel(const int* __restrict__ dst, int* __restrict__ deg, int E) {
    int k = blockIdx.x * blockDim.x + threadIdx.x;
    if (k < E) atomicAdd(&deg[dst[k]], 1);
}

// ---------------- block-level inclusive scan (1024 elems / block) ----------------
__global__ __launch_bounds__(256) void scanA(const int* __restrict__ deg,
                                             int* __restrict__ incl,   // = offs+1
                                             int* __restrict__ bsums) {
    __shared__ int sd[256];
    int tid  = threadIdx.x;
    int base = blockIdx.x * 1024 + tid * 4;
    int v[4];
    int run = 0;
    #pragma unroll
    for (int j = 0; j < 4; ++j) {
        int i = base + j;
        int x = (i < NN) ? deg[i] : 0;
        run += x;
        v[j] = run;
    }
    sd[tid] = run;
    __syncthreads();
    for (int off = 1; off < 256; off <<= 1) {
        int t = (tid >= off) ? sd[tid - off] : 0;
        __syncthreads();
        sd[tid] += t;
        __syncthreads();
    }
    int texcl = sd[tid] - run;   // exclusive prefix of this thread within block
    #pragma unroll
    for (int j = 0; j < 4; ++j) {
        int i = base + j;
        if (i < NN) incl[i] = texcl + v[j];
    }
    if (tid == 255) bsums[blockIdx.x] = sd[255];
}

// ---------------- scan of the 98 block sums (exclusive, in place) ----------------
__global__ void scanB(int* __restrict__ bsums, int nb) {
    __shared__ int sd[128];
    int tid = threadIdx.x;
    int x = (tid < nb) ? bsums[tid] : 0;
    sd[tid] = x;
    __syncthreads();
    for (int off = 1; off < 128; off <<= 1) {
        int t = (tid >= off) ? sd[tid - off] : 0;
        __syncthreads();
        sd[tid] += t;
        __syncthreads();
    }
    if (tid < nb) bsums[tid] = sd[tid] - x;   // exclusive
}

// ---------------- finalize offsets + init scatter cursors ----------------
__global__ __launch_bounds__(256) void scanC(int* __restrict__ offs,
                                             int* __restrict__ cursor,
                                             const int* __restrict__ bsums,
                                             const int* __restrict__ deg) {
    int base = blockIdx.x * 1024 + threadIdx.x * 4;
    int add  = bsums[blockIdx.x];
    #pragma unroll
    for (int j = 0; j < 4; ++j) {
        int i = base + j;
        if (i < NN) {
            int v = offs[i + 1] + add;
            offs[i + 1] = v;
            cursor[i]   = v - deg[i];   // exclusive offset = start of segment i
        }
    }
    if (blockIdx.x == 0 && threadIdx.x == 0) offs[0] = 0;
}

// ---------------- scatter edges into CSR by dst ----------------
__global__ void scatter_kernel(const int* __restrict__ src, const int* __restrict__ dst,
                               int* __restrict__ cursor, int* __restrict__ csr_src, int E) {
    int k = blockIdx.x * blockDim.x + threadIdx.x;
    if (k < E) {
        int d   = dst[k];
        int pos = atomicAdd(&cursor[d], 1);
        csr_src[pos] = src[k];
    }
}

// ---------------- fused per-dst-node: scores + online softmax + aggregation + elu ----------------
__global__ __launch_bounds__(256) void gat_kernel(const float* __restrict__ z,
                                                  const int* __restrict__ offs,
                                                  const int* __restrict__ csr_src,
                                                  float* __restrict__ out) {
    int tid  = threadIdx.x;
    int node = blockIdx.x * 4 + (tid >> 6);   // one wave per node
    int lane = tid & 63;
    int beg = offs[node];
    int end = offs[node + 1];
    float zd = z[(size_t)node * F + lane];
    float m = -INFINITY, ssum = 0.f, h = 0.f;
    for (int j = beg; j < end; ++j) {
        int s    = csr_src[j];
        float zs = z[(size_t)s * F + lane];
        float p  = zs * zd;
        #pragma unroll
        for (int o = 32; o > 0; o >>= 1) p += __shfl_xor(p, o, 64);
        float e  = (p > 0.f) ? p : SLOPE * p;       // leaky_relu
        float nm = fmaxf(m, e);
        float sc = __expf(m - nm);                  // exp(-inf)=0 on first edge
        float ex = __expf(e - nm);
        ssum = ssum * sc + ex;
        h    = h * sc + ex * zs;
        m    = nm;
    }
    float o = (end > beg) ? (h / ssum) : 0.f;
    o = (o > 0.f) ? o : (__expf(o) - 1.f);          // elu (elu(0)=0)
    out[(size_t)node * F + lane] = o;
}

extern "C" void kernel_launch(void* const* d_in, const int* in_sizes, int n_in,
                              void* d_out, int out_size, void* d_ws, size_t ws_size,
                              hipStream_t stream) {
    const float* m_sim = (const float*)d_in[0];
    const float* d_sim = (const float*)d_in[1];
    const float* Wm    = (const float*)d_in[2];
    const float* Wd    = (const float*)d_in[3];
    const int*   src   = (const int*)d_in[4];
    const int*   dst   = (const int*)d_in[5];
    int E = in_sizes[4];
    float* out = (float*)d_out;

    char* ws = (char*)d_ws;
    float* z      = (float*)ws; ws += (size_t)NN * F * 4;
    int*   deg    = (int*)ws;   ws += (size_t)NN * 4;
    int*   offs   = (int*)ws;   ws += (size_t)(NN + 1) * 4;
    int*   cursor = (int*)ws;   ws += (size_t)NN * 4;
    int*   bsums  = (int*)ws;   ws += 128 * 4;
    int*   csr    = (int*)ws;   ws += (size_t)E * 4;

    hipMemsetAsync(deg, 0, (size_t)NN * 4, stream);

    proj_kernel<<<NBM + NBD, 256, 0, stream>>>(m_sim, d_sim, Wm, Wd, z);
    hist_kernel<<<(E + 255) / 256, 256, 0, stream>>>(dst, deg, E);
    int nb = (NN + 1023) / 1024;   // 98
    scanA<<<nb, 256, 0, stream>>>(deg, offs + 1, bsums);
    scanB<<<1, 128, 0, stream>>>(bsums, nb);
    scanC<<<nb, 256, 0, stream>>>(offs, cursor, bsums, deg);
    scatter_kernel<<<(E + 255) / 256, 256, 0, stream>>>(src, dst, cursor, csr, E);
    gat_kernel<<<NN / 4, 256, 0, stream>>>(z, offs, csr, out);
}